// Round 9
// baseline (480.175 us; speedup 1.0000x reference)
//
#include <hip/hip_runtime.h>
#include <hip/hip_bf16.h>
#include <cstdint>
#include <cstddef>

typedef short bf16x8 __attribute__((ext_vector_type(8)));
typedef float f32x4 __attribute__((ext_vector_type(4)));
typedef unsigned short u16x4v __attribute__((ext_vector_type(4)));

__device__ __forceinline__ float bf2f(unsigned short u) {
  union { unsigned int u; float f; } v; v.u = ((unsigned int)u) << 16; return v.f;
}
__device__ __forceinline__ unsigned short f2bf(float f) {
  union { float f; unsigned int u; } v; v.f = f;
  unsigned int r = v.u + 0x7fffu + ((v.u >> 16) & 1u);
  return (unsigned short)(r >> 16);
}
// async global->LDS, 16B per lane
__device__ __forceinline__ void gll16(const void* g, void* l) {
  __builtin_amdgcn_global_load_lds(
      (const __attribute__((address_space(1))) unsigned int*)g,
      (__attribute__((address_space(3))) unsigned int*)l, 16, 0, 0);
}
// DPP rotate-within-row16 + add
template<int CTRL>
__device__ __forceinline__ float dpp_ror_add(float p) {
  int t = __builtin_amdgcn_update_dpp(0, __builtin_bit_cast(int, p), CTRL, 0xf, 0xf, true);
  return p + __builtin_bit_cast(float, t);
}
__device__ __forceinline__ float row16_sum(float p) {
  p = dpp_ror_add<0x121>(p);
  p = dpp_ror_add<0x122>(p);
  p = dpp_ror_add<0x124>(p);
  p = dpp_ror_add<0x128>(p);
  return p;
}

#define LOG2E 1.44269504088896f
#define THR2  11.5415603271f     // 8 * log2(e)

// ---------------- weight transpose+convert ----------------
struct WPack {
  const float* in[6];
  unsigned short* out[6];
  int K[6], Ncol[6];
  int start[7];
};
__global__ __launch_bounds__(256) void convert_all(WPack p) {
  int idx = blockIdx.x * 256 + threadIdx.x;
  #pragma unroll
  for (int s = 0; s < 6; ++s) {
    if (idx >= p.start[s] && idx < p.start[s + 1]) {
      int lidx = idx - p.start[s];
      int k = lidx / p.Ncol[s], n = lidx % p.Ncol[s];
      p.out[s][n * p.K[s] + k] = f2bf(p.in[s][lidx]);
    }
  }
}

// x (f32) -> bf16, vectorized 4-wide
__global__ __launch_bounds__(256) void convert_x(const float* __restrict__ in,
                                                 unsigned short* __restrict__ out, int n4) {
  int i = blockIdx.x * 256 + threadIdx.x;
  if (i < n4) {
    f32x4 v = *reinterpret_cast<const f32x4*>(in + (size_t)i * 4);
    u16x4v o;
    #pragma unroll
    for (int j = 0; j < 4; ++j) o[j] = f2bf(v[j]);
    *reinterpret_cast<u16x4v*>(out + (size_t)i * 4) = o;
  }
}

// ---------------- GEMM: C[M,Ncol] = A[M,K] @ Wt[Ncol,K]^T (f32 acc, bf16 out)
// A,B bf16 via global_load_lds (A rows valid/padded to gx*128).
template<int BN, int WAVES_M, int WAVES_N>
__global__ __launch_bounds__(256) void gemm_dual(
    const unsigned short* __restrict__ A,
    const unsigned short* __restrict__ BtL, const unsigned short* __restrict__ BtR,
    unsigned short* __restrict__ outL, unsigned short* __restrict__ outR,
    int M, int K, int Ncol) {
  constexpr int BM = 128, BK = 64;
  constexpr int WTM = BM / WAVES_M, WTN = BN / WAVES_N;
  constexpr int MR = WTM / 16, NR = WTN / 16;
  const unsigned short* __restrict__ Bt = blockIdx.z ? BtR : BtL;
  unsigned short* __restrict__ outp = blockIdx.z ? outR : outL;

  __shared__ alignas(16) unsigned short lAt[BM * BK];
  __shared__ alignas(16) unsigned short lBt[BN * BK];

  int t = threadIdx.x;
  int lane = t & 63, wid = t >> 6;
  int wm = wid / WAVES_N, wn = wid % WAVES_N;
  int rowBase = blockIdx.x * BM;
  int colBase = blockIdx.y * BN;

  f32x4 acc[MR][NR] = {};

  for (int k0 = 0; k0 < K; k0 += BK) {
    #pragma unroll
    for (int p = 0; p < BM / 32; ++p) {
      int chunk = wid * (BM / 32) + p;
      int row = chunk * 8 + (lane >> 3);
      int c = (lane & 7) ^ (row & 7);   // pre-swizzled source, linear LDS dest
      gll16(A + (size_t)(rowBase + row) * K + k0 + c * 8, &lAt[chunk * 512]);
    }
    #pragma unroll
    for (int p = 0; p < BN / 32; ++p) {
      int chunk = wid * (BN / 32) + p;
      int row = chunk * 8 + (lane >> 3);
      int c = (lane & 7) ^ (row & 7);
      gll16(Bt + (size_t)(colBase + row) * K + k0 + c * 8, &lBt[chunk * 512]);
    }
    __syncthreads();
    #pragma unroll
    for (int kk = 0; kk < 2; ++kk) {
      bf16x8 af[MR], bfr[NR];
      int cidx = kk * 4 + (lane >> 4);
      #pragma unroll
      for (int mi = 0; mi < MR; ++mi) {
        int row = wm * WTM + mi * 16 + (lane & 15);
        af[mi] = *reinterpret_cast<const bf16x8*>(&lAt[row * 64 + ((cidx ^ (row & 7)) * 8)]);
      }
      #pragma unroll
      for (int ni = 0; ni < NR; ++ni) {
        int row = wn * WTN + ni * 16 + (lane & 15);
        bfr[ni] = *reinterpret_cast<const bf16x8*>(&lBt[row * 64 + ((cidx ^ (row & 7)) * 8)]);
      }
      #pragma unroll
      for (int mi = 0; mi < MR; ++mi)
        #pragma unroll
        for (int ni = 0; ni < NR; ++ni)
          acc[mi][ni] = __builtin_amdgcn_mfma_f32_16x16x32_bf16(af[mi], bfr[ni], acc[mi][ni], 0, 0, 0);
    }
    __syncthreads();
  }
  #pragma unroll
  for (int mi = 0; mi < MR; ++mi)
    #pragma unroll
    for (int ni = 0; ni < NR; ++ni) {
      int col = colBase + wn * WTN + ni * 16 + (lane & 15);
      #pragma unroll
      for (int r = 0; r < 4; ++r) {
        int row = rowBase + wm * WTM + mi * 16 + (lane >> 4) * 4 + r;
        if (row < M) outp[(size_t)row * Ncol + col] = f2bf(acc[mi][ni][r]);
      }
    }
}

// ---------------- CSR build (+ LPT folded in) ----------------
__global__ __launch_bounds__(256) void hist_kernel(const int* __restrict__ dst, int* __restrict__ counts, int E) {
  int e = blockIdx.x * 256 + threadIdx.x;
  if (e < E) atomicAdd(&counts[dst[e]], 1);
}

__global__ __launch_bounds__(256) void scan_block_deg(
    const int* __restrict__ in, int* __restrict__ out, int* __restrict__ sums,
    int* __restrict__ binTotal, int* __restrict__ blockBase, int n) {
  __shared__ int lh[256];
  __shared__ int wsum[4];
  lh[threadIdx.x] = 0;
  __syncthreads();
  int i = blockIdx.x * 256 + threadIdx.x;
  int lane = threadIdx.x & 63, wid = threadIdx.x >> 6;
  int v = (i < n) ? in[i] : 0;
  if (i < n) atomicAdd(&lh[v < 255 ? v : 255], 1);
  int s = v;
  #pragma unroll
  for (int d = 1; d < 64; d <<= 1) { int tt = __shfl_up(s, d); if (lane >= d) s += tt; }
  if (lane == 63) wsum[wid] = s;
  __syncthreads();
  int off = 0;
  for (int w = 0; w < wid; ++w) off += wsum[w];
  if (i < n) out[i] = off + s - v;
  if (threadIdx.x == 255) sums[blockIdx.x] = off + s;
  int c = lh[threadIdx.x];
  blockBase[blockIdx.x * 256 + threadIdx.x] = c ? atomicAdd(&binTotal[threadIdx.x], c) : 0;
}

__global__ __launch_bounds__(256) void scan2_offsets(
    const int* __restrict__ bsums, int* __restrict__ boffs,
    const int* __restrict__ binTotal, int* __restrict__ binStart, int n) {
  __shared__ int ws[4];
  int t = threadIdx.x;
  int lane = t & 63, w = t >> 6;
  {
    int v = (t < n) ? bsums[t] : 0;
    int s = v;
    #pragma unroll
    for (int d = 1; d < 64; d <<= 1) { int tt = __shfl_up(s, d); if (lane >= d) s += tt; }
    if (lane == 63) ws[w] = s;
    __syncthreads();
    int off = 0;
    for (int u = 0; u < w; ++u) off += ws[u];
    if (t < n) boffs[t] = off + s - v;
    __syncthreads();
  }
  {
    int v = binTotal[255 - t];
    int s = v;
    #pragma unroll
    for (int d = 1; d < 64; d <<= 1) { int tt = __shfl_up(s, d); if (lane >= d) s += tt; }
    if (lane == 63) ws[w] = s;
    __syncthreads();
    int off = 0;
    for (int u = 0; u < w; ++u) off += ws[u];
    binStart[255 - t] = off + s - v;
  }
}

__global__ __launch_bounds__(256) void scan_add_place(
    int* __restrict__ rs, const int* __restrict__ boffs, int* __restrict__ cursor,
    const int* __restrict__ counts, const int* __restrict__ binStart,
    const int* __restrict__ blockBase, int* __restrict__ perm, int n, int E) {
  __shared__ int lcur[256];
  lcur[threadIdx.x] = binStart[threadIdx.x] + blockBase[blockIdx.x * 256 + threadIdx.x];
  __syncthreads();
  int i = blockIdx.x * 256 + threadIdx.x;
  if (i < n) {
    int v = rs[i] + boffs[blockIdx.x];
    rs[i] = v;
    cursor[i] = v;
    int d = counts[i]; if (d > 255) d = 255;
    perm[atomicAdd(&lcur[d], 1)] = i;
  }
  if (i == 0) rs[n] = E;
}

__global__ __launch_bounds__(256) void scatter_kernel(const int* __restrict__ src, const int* __restrict__ dst,
                                                      int* __restrict__ cursor, int* __restrict__ csr, int E) {
  int e = blockIdx.x * 256 + threadIdx.x;
  if (e < E) {
    int p = atomicAdd(&cursor[dst[e]], 1);
    csr[p] = src[e];
  }
}

// ---------------- edge aggregation ----------------
// H=4: one wave per dst node, LPT order; scalar f32 math, exp2 domain,
// self-loop hoisted out of the clean [s0,s1) loop, 6-deep unroll.
template<bool SELF, bool RELU>
__global__ __launch_bounds__(256) void edge_agg4(
    const unsigned short* __restrict__ xl, const unsigned short* __restrict__ xr,
    const float* __restrict__ att, const float* __restrict__ bias,
    const int* __restrict__ rowstart, const int* __restrict__ csr,
    const int* __restrict__ perm,
    unsigned short* __restrict__ out, int N) {
  int wave = threadIdx.x >> 6, lane = threadIdx.x & 63;
  int gid = blockIdx.x * 4 + wave;
  if (gid >= N) return;
  int node = perm[gid];

  float attv[4];
  {
    f32x4 a4 = *reinterpret_cast<const f32x4*>(att + lane * 4);
    #pragma unroll
    for (int j = 0; j < 4; ++j) attv[j] = a4[j] * LOG2E;
  }
  float xrv[4];
  {
    u16x4v r4 = *reinterpret_cast<const u16x4v*>(xr + (size_t)node * 256 + lane * 4);
    #pragma unroll
    for (int j = 0; j < 4; ++j) xrv[j] = bf2f(r4[j]);
  }

  int s0 = rowstart[node], s1 = rowstart[node + 1];

  auto score4 = [&](u16x4v raw, float* xv) -> float {
    float p = 0.f;
    #pragma unroll
    for (int j = 0; j < 4; ++j) {
      xv[j] = bf2f(raw[j]);
      float tv = xv[j] + xrv[j];
      tv = fmaxf(tv, 0.2f * tv);
      p = fmaf(tv, attv[j], p);
    }
    return row16_sum(p);
  };

  float m, l;
  float acc[4];

  // init: self-loop (SELF) or first csr edge; deg-0 handled for !SELF
  if constexpr (SELF) {
    u16x4v raw = *reinterpret_cast<const u16x4v*>(xl + (size_t)node * 256 + lane * 4);
    float xv[4];
    m = score4(raw, xv);
    l = 1.f;
    #pragma unroll
    for (int j = 0; j < 4; ++j) acc[j] = xv[j];
  } else {
    if (s0 >= s1) {
      u16x4v w4;
      f32x4 b4 = *reinterpret_cast<const f32x4*>(bias + lane * 4);
      #pragma unroll
      for (int j = 0; j < 4; ++j) {
        float o = b4[j];
        if (RELU) o = fmaxf(o, 0.f);
        w4[j] = f2bf(o);
      }
      *reinterpret_cast<u16x4v*>(out + (size_t)node * 256 + lane * 4) = w4;
      return;
    }
    u16x4v raw = *reinterpret_cast<const u16x4v*>(xl + (size_t)csr[s0] * 256 + lane * 4);
    float xv[4];
    m = score4(raw, xv);
    l = 1.f;
    #pragma unroll
    for (int j = 0; j < 4; ++j) acc[j] = xv[j];
    ++s0;
  }

  int i = s0;
  for (; i + 6 <= s1; i += 6) {
    u16x4v raw[6];
    #pragma unroll
    for (int q = 0; q < 6; ++q)
      raw[q] = *reinterpret_cast<const u16x4v*>(xl + (size_t)csr[i + q] * 256 + lane * 4);
    float xv[6][4], p_[6];
    #pragma unroll
    for (int q = 0; q < 6; ++q) p_[q] = score4(raw[q], xv[q]);
    float mx = fmaxf(fmaxf(fmaxf(p_[0], p_[1]), fmaxf(p_[2], p_[3])), fmaxf(p_[4], p_[5]));
    if (__any(mx > m + THR2)) {
      float mn = fmaxf(m, mx);
      float sc = __builtin_amdgcn_exp2f(m - mn);
      l *= sc;
      #pragma unroll
      for (int j = 0; j < 4; ++j) acc[j] *= sc;
      m = mn;
    }
    float w_[6];
    #pragma unroll
    for (int q = 0; q < 6; ++q) w_[q] = __builtin_amdgcn_exp2f(p_[q] - m);
    l += ((w_[0] + w_[1]) + (w_[2] + w_[3])) + (w_[4] + w_[5]);
    #pragma unroll
    for (int j = 0; j < 4; ++j) {
      float a = acc[j];
      #pragma unroll
      for (int q = 0; q < 6; ++q) a = fmaf(w_[q], xv[q][j], a);
      acc[j] = a;
    }
  }
  for (; i < s1; ++i) {
    u16x4v raw = *reinterpret_cast<const u16x4v*>(xl + (size_t)csr[i] * 256 + lane * 4);
    float xv[4];
    float p = score4(raw, xv);
    if (__any(p > m + THR2)) {
      float mn = fmaxf(m, p);
      float sc = __builtin_amdgcn_exp2f(m - mn);
      l *= sc;
      #pragma unroll
      for (int j = 0; j < 4; ++j) acc[j] *= sc;
      m = mn;
    }
    float w = __builtin_amdgcn_exp2f(p - m);
    l += w;
    #pragma unroll
    for (int j = 0; j < 4; ++j) acc[j] = fmaf(w, xv[j], acc[j]);
  }

  float rec = 1.f / (l + 1e-16f);
  f32x4 b4 = *reinterpret_cast<const f32x4*>(bias + lane * 4);
  u16x4v w4;
  #pragma unroll
  for (int j = 0; j < 4; ++j) {
    float o = fmaf(acc[j], rec, b4[j]);
    if (RELU) o = fmaxf(o, 0.f);
    w4[j] = f2bf(o);
  }
  *reinterpret_cast<u16x4v*>(out + (size_t)node * 256 + lane * 4) = w4;
}

// H=1: one wave per dst node; 8-deep unroll, self hoisted, exp2 domain.
template<bool SELF, bool RELU>
__global__ __launch_bounds__(256) void edge_agg1(
    const unsigned short* __restrict__ xl, const unsigned short* __restrict__ xr,
    const float* __restrict__ att, const float* __restrict__ bias,
    const int* __restrict__ rowstart, const int* __restrict__ csr,
    const int* __restrict__ perm,
    unsigned short* __restrict__ out, int N) {
  int wave = threadIdx.x >> 6, lane = threadIdx.x & 63;
  int gid = blockIdx.x * 4 + wave;
  if (gid >= N) return;
  int node = perm[gid];

  float attv = att[lane] * LOG2E;
  float xrv = bf2f(xr[(size_t)node * 64 + lane]);

  int s0 = rowstart[node], s1 = rowstart[node + 1];

  auto score = [&](float xv) {
    float tv = xv + xrv;
    tv = fmaxf(tv, 0.2f * tv);
    float p = row16_sum(tv * attv);
    p += __shfl_xor(p, 16);
    p += __shfl_xor(p, 32);
    return p;
  };

  float m, l, acc;
  if constexpr (SELF) {
    float xv = bf2f(xl[(size_t)node * 64 + lane]);
    m = score(xv); l = 1.f; acc = xv;
  } else {
    if (s0 >= s1) {
      float o = bias[lane];
      if (RELU) o = fmaxf(o, 0.f);
      out[(size_t)node * 64 + lane] = f2bf(o);
      return;
    }
    float xv = bf2f(xl[(size_t)csr[s0] * 64 + lane]);
    m = score(xv); l = 1.f; acc = xv;
    ++s0;
  }

  int i = s0;
  for (; i + 8 <= s1; i += 8) {
    float x_[8], p_[8], w_[8];
    #pragma unroll
    for (int q = 0; q < 8; ++q) x_[q] = bf2f(xl[(size_t)csr[i + q] * 64 + lane]);
    #pragma unroll
    for (int q = 0; q < 8; ++q) p_[q] = score(x_[q]);
    float mx = fmaxf(fmaxf(fmaxf(p_[0], p_[1]), fmaxf(p_[2], p_[3])),
                     fmaxf(fmaxf(p_[4], p_[5]), fmaxf(p_[6], p_[7])));
    if (__any(mx > m + THR2)) {
      float mn = fmaxf(m, mx);
      float sc = __builtin_amdgcn_exp2f(m - mn);
      l *= sc; acc *= sc; m = mn;
    }
    #pragma unroll
    for (int q = 0; q < 8; ++q) w_[q] = __builtin_amdgcn_exp2f(p_[q] - m);
    l += ((w_[0] + w_[1]) + (w_[2] + w_[3])) + ((w_[4] + w_[5]) + (w_[6] + w_[7]));
    float a = acc;
    #pragma unroll
    for (int q = 0; q < 8; ++q) a = fmaf(w_[q], x_[q], a);
    acc = a;
  }
  for (; i < s1; ++i) {
    float xv = bf2f(xl[(size_t)csr[i] * 64 + lane]);
    float p = score(xv);
    if (__any(p > m + THR2)) {
      float mn = fmaxf(m, p);
      float sc = __builtin_amdgcn_exp2f(m - mn);
      l *= sc; acc *= sc; m = mn;
    }
    float w = __builtin_amdgcn_exp2f(p - m);
    l += w;
    acc = fmaf(w, xv, acc);
  }

  float rec = 1.f / (l + 1e-16f);
  float o = fmaf(acc, rec, bias[lane]);
  if (RELU) o = fmaxf(o, 0.f);
  out[(size_t)node * 64 + lane] = f2bf(o);
}

// ---------------- fused mean-pool + MLP + softmax: one block per graph ----------------
__global__ __launch_bounds__(256) void pool_mlp(
    const unsigned short* __restrict__ h, const int* __restrict__ batch,
    const float* __restrict__ w1, const float* __restrict__ b1,
    const float* __restrict__ w2, const float* __restrict__ b2,
    const float* __restrict__ w3, const float* __restrict__ b3,
    float* __restrict__ out, int N) {
  int g = blockIdx.x;
  int lo = 0, hi = N;
  while (lo < hi) { int mid = (lo + hi) >> 1; if (batch[mid] < g) lo = mid + 1; else hi = mid; }
  int n0 = lo;
  hi = N;
  while (lo < hi) { int mid = (lo + hi) >> 1; if (batch[mid] < g + 1) lo = mid + 1; else hi = mid; }
  int n1 = lo;

  int t = threadIdx.x;
  int c2 = t & 31, r = t >> 5;
  float ax = 0.f, ay = 0.f;
  for (int n = n0 + r; n < n1; n += 8) {
    unsigned int u = *reinterpret_cast<const unsigned int*>(h + (size_t)n * 64 + c2 * 2);
    ax += bf2f((unsigned short)(u & 0xffffu));
    ay += bf2f((unsigned short)(u >> 16));
  }
  __shared__ float redx[8][32], redy[8][32];
  __shared__ float sh[64];
  redx[r][c2] = ax; redy[r][c2] = ay;
  __syncthreads();
  if (t < 64) {
    int lane = t;
    float s = 0.f;
    #pragma unroll
    for (int q = 0; q < 8; ++q) s += (lane & 1) ? redy[q][lane >> 1] : redx[q][lane >> 1];
    float cnt = fmaxf((float)(n1 - n0), 1.f);
    sh[lane] = s / cnt;
    float h1 = b1[lane];
    for (int k = 0; k < 64; ++k) h1 = fmaf(sh[k], w1[k * 64 + lane], h1);
    h1 = fmaxf(h1, 0.f);
    sh[lane] = h1;
    float h2 = b2[lane];
    for (int k = 0; k < 64; ++k) h2 = fmaf(sh[k], w2[k * 64 + lane], h2);
    h2 = fmaxf(h2, 0.f);
    sh[lane] = h2;
    float lg = -INFINITY;
    if (lane < 12) {
      lg = b3[lane];
      for (int k = 0; k < 64; ++k) lg = fmaf(sh[k], w3[k * 12 + lane], lg);
    }
    float mx = lg;
    #pragma unroll
    for (int msk = 1; msk < 64; msk <<= 1) mx = fmaxf(mx, __shfl_xor(mx, msk));
    float ex = (lane < 12) ? __expf(lg - mx) : 0.f;
    float sm = ex;
    #pragma unroll
    for (int msk = 1; msk < 64; msk <<= 1) sm += __shfl_xor(sm, msk);
    if (lane < 12) out[(size_t)g * 12 + lane] = ex / sm;
  }
}

// ---------------- host ----------------
extern "C" void kernel_launch(void* const* d_in, const int* in_sizes, int n_in,
                              void* d_out, int out_size, void* d_ws, size_t ws_size,
                              hipStream_t stream) {
  const float* x    = (const float*)d_in[0];
  const int* edge   = (const int*)d_in[1];
  const int* batch  = (const int*)d_in[2];
  const float* W1l  = (const float*)d_in[3];
  const float* W1r  = (const float*)d_in[4];
  const float* a1   = (const float*)d_in[5];
  const float* b1   = (const float*)d_in[6];
  const float* W2l  = (const float*)d_in[7];
  const float* W2r  = (const float*)d_in[8];
  const float* a2   = (const float*)d_in[9];
  const float* b2   = (const float*)d_in[10];
  const float* W3l  = (const float*)d_in[11];
  const float* W3r  = (const float*)d_in[12];
  const float* a3   = (const float*)d_in[13];
  const float* b3   = (const float*)d_in[14];
  const float* lw1  = (const float*)d_in[15];
  const float* lb1  = (const float*)d_in[16];
  const float* lw2  = (const float*)d_in[17];
  const float* lb2  = (const float*)d_in[18];
  const float* lw3  = (const float*)d_in[19];
  const float* lb3  = (const float*)d_in[20];

  const int E = in_sizes[1] / 2;
  const int N = in_sizes[2];
  const int F0 = in_sizes[0] / N;   // 128
  const int G = out_size / 12;      // 512
  const int* src = edge;
  const int* dst = edge + E;

  const int gx = (N + 127) / 128;
  const int Mpad = gx * 128;
  const int nb = (N + 255) / 256;

  // workspace carve (256B aligned)
  char* p = (char*)d_ws;
  auto alloc = [&](size_t bytes) { char* q = p; p += (bytes + 255) & ~(size_t)255; return q; };
  unsigned short* bufA = (unsigned short*)alloc((size_t)Mpad * 256 * 2);
  unsigned short* bufB = (unsigned short*)alloc((size_t)Mpad * 256 * 2);
  unsigned short* bufH = (unsigned short*)alloc((size_t)Mpad * 256 * 2);
  unsigned short* xbf  = (unsigned short*)alloc((size_t)Mpad * 128 * 2);
  unsigned short* Wt1L = (unsigned short*)alloc(128 * 256 * 2);
  unsigned short* Wt1R = (unsigned short*)alloc(128 * 256 * 2);
  unsigned short* Wt2L = (unsigned short*)alloc(256 * 256 * 2);
  unsigned short* Wt2R = (unsigned short*)alloc(256 * 256 * 2);
  unsigned short* Wt3L = (unsigned short*)alloc(256 * 64 * 2);
  unsigned short* Wt3R = (unsigned short*)alloc(256 * 64 * 2);
  int* counts    = (int*)alloc((size_t)N * 4);      // contiguous with binTotal for one memset
  int* binTotal  = (int*)alloc(256 * 4);
  int* binStart  = (int*)alloc(256 * 4);
  int* blockBase = (int*)alloc((size_t)nb * 256 * 4);
  int* rowstart  = (int*)alloc((size_t)(N + 1) * 4);
  int* cursor    = (int*)alloc((size_t)N * 4);
  int* perm      = (int*)alloc((size_t)N * 4);
  int* bsums     = (int*)alloc(4096 * 4);
  int* boffs     = (int*)alloc(4096 * 4);
  int* csr       = (int*)alloc((size_t)E * 4);

  // ---- CSR by dst + LPT perm (folded) ----
  size_t countsPad = ((size_t)N * 4 + 255) & ~(size_t)255;
  hipMemsetAsync(counts, 0, countsPad + 256 * 4, stream);
  hist_kernel<<<(E + 255) / 256, 256, 0, stream>>>(dst, counts, E);
  scan_block_deg<<<nb, 256, 0, stream>>>(counts, rowstart, bsums, binTotal, blockBase, N);
  scan2_offsets<<<1, 256, 0, stream>>>(bsums, boffs, binTotal, binStart, nb);
  scan_add_place<<<nb, 256, 0, stream>>>(rowstart, boffs, cursor, counts, binStart, blockBase, perm, N, E);
  scatter_kernel<<<(E + 255) / 256, 256, 0, stream>>>(src, dst, cursor, csr, E);

  // ---- weight transposes + x conversion ----
  {
    WPack wp;
    const float* ins[6] = {W1l, W1r, W2l, W2r, W3l, W3r};
    unsigned short* outs[6] = {Wt1L, Wt1R, Wt2L, Wt2R, Wt3L, Wt3R};
    int Ks[6] = {F0, F0, 256, 256, 256, 256};
    int Ns[6] = {256, 256, 256, 256, 64, 64};
    int acc0 = 0;
    for (int s = 0; s < 6; ++s) {
      wp.in[s] = ins[s]; wp.out[s] = outs[s]; wp.K[s] = Ks[s]; wp.Ncol[s] = Ns[s];
      wp.start[s] = acc0; acc0 += Ks[s] * Ns[s];
    }
    wp.start[6] = acc0;
    convert_all<<<(acc0 + 255) / 256, 256, 0, stream>>>(wp);
  }
  {
    int n4 = (N * F0) / 4;
    convert_x<<<(n4 + 255) / 256, 256, 0, stream>>>(x, xbf, n4);
  }

  int ne = (N + 3) / 4;

  // ---- conv1: K=128, Ncol=256, no self loops, relu; A = xbf (bf16, GLL) ----
  gemm_dual<128, 2, 2><<<dim3(gx, 2, 2), 256, 0, stream>>>(xbf, Wt1L, Wt1R, bufA, bufB, N, F0, 256);
  edge_agg4<false, true><<<ne, 256, 0, stream>>>(bufA, bufB, a1, b1, rowstart, csr, perm, bufH, N);

  // ---- conv2: K=256, Ncol=256, self loops, relu ----
  gemm_dual<128, 2, 2><<<dim3(gx, 2, 2), 256, 0, stream>>>(bufH, Wt2L, Wt2R, bufA, bufB, N, 256, 256);
  edge_agg4<true, true><<<ne, 256, 0, stream>>>(bufA, bufB, a2, b2, rowstart, csr, perm, bufH, N);

  // ---- conv3: K=256, Ncol=64, self loops, no relu ----
  gemm_dual<64, 4, 1><<<dim3(gx, 1, 2), 256, 0, stream>>>(bufH, Wt3L, Wt3R, bufA, bufB, N, 256, 64);
  edge_agg1<true, false><<<ne, 256, 0, stream>>>(bufA, bufB, a3, b3, rowstart, csr, perm, bufH, N);

  // ---- fused mean pool + MLP head + softmax ----
  pool_mlp<<<G, 256, 0, stream>>>(bufH, batch, lw1, lb1, lw2, lb2, lw3, lb3,
                                  (float*)d_out, N);
}

// Round 10
// 460.835 us; speedup vs baseline: 1.0420x; 1.0420x over previous
//
#include <hip/hip_runtime.h>
#include <hip/hip_bf16.h>
#include <cstdint>
#include <cstddef>

typedef short bf16x8 __attribute__((ext_vector_type(8)));
typedef float f32x4 __attribute__((ext_vector_type(4)));
typedef unsigned short u16x4v __attribute__((ext_vector_type(4)));

__device__ __forceinline__ float bf2f(unsigned short u) {
  union { unsigned int u; float f; } v; v.u = ((unsigned int)u) << 16; return v.f;
}
__device__ __forceinline__ unsigned short f2bf(float f) {
  union { float f; unsigned int u; } v; v.f = f;
  unsigned int r = v.u + 0x7fffu + ((v.u >> 16) & 1u);
  return (unsigned short)(r >> 16);
}
// async global->LDS, 16B per lane
__device__ __forceinline__ void gll16(const void* g, void* l) {
  __builtin_amdgcn_global_load_lds(
      (const __attribute__((address_space(1))) unsigned int*)g,
      (__attribute__((address_space(3))) unsigned int*)l, 16, 0, 0);
}
// DPP rotate-within-row16 + add
template<int CTRL>
__device__ __forceinline__ float dpp_ror_add(float p) {
  int t = __builtin_amdgcn_update_dpp(0, __builtin_bit_cast(int, p), CTRL, 0xf, 0xf, true);
  return p + __builtin_bit_cast(float, t);
}
__device__ __forceinline__ float row16_sum(float p) {
  p = dpp_ror_add<0x121>(p);
  p = dpp_ror_add<0x122>(p);
  p = dpp_ror_add<0x124>(p);
  p = dpp_ror_add<0x128>(p);
  return p;
}

#define LOG2E 1.44269504088896f
#define THR2  11.5415603271f     // 8 * log2(e)

// ---------------- weight transpose+convert ----------------
struct WPack {
  const float* in[6];
  unsigned short* out[6];
  int K[6], Ncol[6];
  int start[7];
};
__global__ __launch_bounds__(256) void convert_all(WPack p) {
  int idx = blockIdx.x * 256 + threadIdx.x;
  #pragma unroll
  for (int s = 0; s < 6; ++s) {
    if (idx >= p.start[s] && idx < p.start[s + 1]) {
      int lidx = idx - p.start[s];
      int k = lidx / p.Ncol[s], n = lidx % p.Ncol[s];
      p.out[s][n * p.K[s] + k] = f2bf(p.in[s][lidx]);
    }
  }
}

// x (f32) -> bf16, vectorized 4-wide
__global__ __launch_bounds__(256) void convert_x(const float* __restrict__ in,
                                                 unsigned short* __restrict__ out, int n4) {
  int i = blockIdx.x * 256 + threadIdx.x;
  if (i < n4) {
    f32x4 v = *reinterpret_cast<const f32x4*>(in + (size_t)i * 4);
    u16x4v o;
    #pragma unroll
    for (int j = 0; j < 4; ++j) o[j] = f2bf(v[j]);
    *reinterpret_cast<u16x4v*>(out + (size_t)i * 4) = o;
  }
}

// ---------------- GEMM: C[M,Ncol] = A[M,K] @ Wt[Ncol,K]^T (f32 acc, bf16 out)
template<int BN, int WAVES_M, int WAVES_N>
__global__ __launch_bounds__(256) void gemm_dual(
    const unsigned short* __restrict__ A,
    const unsigned short* __restrict__ BtL, const unsigned short* __restrict__ BtR,
    unsigned short* __restrict__ outL, unsigned short* __restrict__ outR,
    int M, int K, int Ncol) {
  constexpr int BM = 128, BK = 64;
  constexpr int WTM = BM / WAVES_M, WTN = BN / WAVES_N;
  constexpr int MR = WTM / 16, NR = WTN / 16;
  const unsigned short* __restrict__ Bt = blockIdx.z ? BtR : BtL;
  unsigned short* __restrict__ outp = blockIdx.z ? outR : outL;

  __shared__ alignas(16) unsigned short lAt[BM * BK];
  __shared__ alignas(16) unsigned short lBt[BN * BK];

  int t = threadIdx.x;
  int lane = t & 63, wid = t >> 6;
  int wm = wid / WAVES_N, wn = wid % WAVES_N;
  int rowBase = blockIdx.x * BM;
  int colBase = blockIdx.y * BN;

  f32x4 acc[MR][NR] = {};

  for (int k0 = 0; k0 < K; k0 += BK) {
    #pragma unroll
    for (int p = 0; p < BM / 32; ++p) {
      int chunk = wid * (BM / 32) + p;
      int row = chunk * 8 + (lane >> 3);
      int c = (lane & 7) ^ (row & 7);   // pre-swizzled source, linear LDS dest
      gll16(A + (size_t)(rowBase + row) * K + k0 + c * 8, &lAt[chunk * 512]);
    }
    #pragma unroll
    for (int p = 0; p < BN / 32; ++p) {
      int chunk = wid * (BN / 32) + p;
      int row = chunk * 8 + (lane >> 3);
      int c = (lane & 7) ^ (row & 7);
      gll16(Bt + (size_t)(colBase + row) * K + k0 + c * 8, &lBt[chunk * 512]);
    }
    __syncthreads();
    #pragma unroll
    for (int kk = 0; kk < 2; ++kk) {
      bf16x8 af[MR], bfr[NR];
      int cidx = kk * 4 + (lane >> 4);
      #pragma unroll
      for (int mi = 0; mi < MR; ++mi) {
        int row = wm * WTM + mi * 16 + (lane & 15);
        af[mi] = *reinterpret_cast<const bf16x8*>(&lAt[row * 64 + ((cidx ^ (row & 7)) * 8)]);
      }
      #pragma unroll
      for (int ni = 0; ni < NR; ++ni) {
        int row = wn * WTN + ni * 16 + (lane & 15);
        bfr[ni] = *reinterpret_cast<const bf16x8*>(&lBt[row * 64 + ((cidx ^ (row & 7)) * 8)]);
      }
      #pragma unroll
      for (int mi = 0; mi < MR; ++mi)
        #pragma unroll
        for (int ni = 0; ni < NR; ++ni)
          acc[mi][ni] = __builtin_amdgcn_mfma_f32_16x16x32_bf16(af[mi], bfr[ni], acc[mi][ni], 0, 0, 0);
    }
    __syncthreads();
  }
  #pragma unroll
  for (int mi = 0; mi < MR; ++mi)
    #pragma unroll
    for (int ni = 0; ni < NR; ++ni) {
      int col = colBase + wn * WTN + ni * 16 + (lane & 15);
      #pragma unroll
      for (int r = 0; r < 4; ++r) {
        int row = rowBase + wm * WTM + mi * 16 + (lane >> 4) * 4 + r;
        if (row < M) outp[(size_t)row * Ncol + col] = f2bf(acc[mi][ni][r]);
      }
    }
}

// ---------------- CSR build (+ LPT folded in) ----------------
__global__ __launch_bounds__(256) void hist_kernel(const int* __restrict__ dst, int* __restrict__ counts, int E) {
  int e = blockIdx.x * 256 + threadIdx.x;
  if (e < E) atomicAdd(&counts[dst[e]], 1);
}

__global__ __launch_bounds__(256) void scan_block_deg(
    const int* __restrict__ in, int* __restrict__ out, int* __restrict__ sums,
    int* __restrict__ binTotal, int* __restrict__ blockBase, int n) {
  __shared__ int lh[256];
  __shared__ int wsum[4];
  lh[threadIdx.x] = 0;
  __syncthreads();
  int i = blockIdx.x * 256 + threadIdx.x;
  int lane = threadIdx.x & 63, wid = threadIdx.x >> 6;
  int v = (i < n) ? in[i] : 0;
  if (i < n) atomicAdd(&lh[v < 255 ? v : 255], 1);
  int s = v;
  #pragma unroll
  for (int d = 1; d < 64; d <<= 1) { int tt = __shfl_up(s, d); if (lane >= d) s += tt; }
  if (lane == 63) wsum[wid] = s;
  __syncthreads();
  int off = 0;
  for (int w = 0; w < wid; ++w) off += wsum[w];
  if (i < n) out[i] = off + s - v;
  if (threadIdx.x == 255) sums[blockIdx.x] = off + s;
  int c = lh[threadIdx.x];
  blockBase[blockIdx.x * 256 + threadIdx.x] = c ? atomicAdd(&binTotal[threadIdx.x], c) : 0;
}

__global__ __launch_bounds__(256) void scan2_offsets(
    const int* __restrict__ bsums, int* __restrict__ boffs,
    const int* __restrict__ binTotal, int* __restrict__ binStart, int n) {
  __shared__ int ws[4];
  int t = threadIdx.x;
  int lane = t & 63, w = t >> 6;
  {
    int v = (t < n) ? bsums[t] : 0;
    int s = v;
    #pragma unroll
    for (int d = 1; d < 64; d <<= 1) { int tt = __shfl_up(s, d); if (lane >= d) s += tt; }
    if (lane == 63) ws[w] = s;
    __syncthreads();
    int off = 0;
    for (int u = 0; u < w; ++u) off += ws[u];
    if (t < n) boffs[t] = off + s - v;
    __syncthreads();
  }
  {
    int v = binTotal[255 - t];
    int s = v;
    #pragma unroll
    for (int d = 1; d < 64; d <<= 1) { int tt = __shfl_up(s, d); if (lane >= d) s += tt; }
    if (lane == 63) ws[w] = s;
    __syncthreads();
    int off = 0;
    for (int u = 0; u < w; ++u) off += ws[u];
    binStart[255 - t] = off + s - v;
  }
}

__global__ __launch_bounds__(256) void scan_add_place(
    int* __restrict__ rs, const int* __restrict__ boffs, int* __restrict__ cursor,
    const int* __restrict__ counts, const int* __restrict__ binStart,
    const int* __restrict__ blockBase, int* __restrict__ perm, int n, int E) {
  __shared__ int lcur[256];
  lcur[threadIdx.x] = binStart[threadIdx.x] + blockBase[blockIdx.x * 256 + threadIdx.x];
  __syncthreads();
  int i = blockIdx.x * 256 + threadIdx.x;
  if (i < n) {
    int v = rs[i] + boffs[blockIdx.x];
    rs[i] = v;
    cursor[i] = v;
    int d = counts[i]; if (d > 255) d = 255;
    perm[atomicAdd(&lcur[d], 1)] = i;
  }
  if (i == 0) rs[n] = E;
}

__global__ __launch_bounds__(256) void scatter_kernel(const int* __restrict__ src, const int* __restrict__ dst,
                                                      int* __restrict__ cursor, int* __restrict__ csr, int E) {
  int e = blockIdx.x * 256 + threadIdx.x;
  if (e < E) {
    int p = atomicAdd(&cursor[dst[e]], 1);
    csr[p] = src[e];
  }
}

// ---------------- edge aggregation (r7 structure + exp2 + scalar csr idx) ----------------
// H=4: one wave per dst node, LPT order via perm; 4-deep unroll.
template<bool SELF, bool RELU>
__global__ __launch_bounds__(256) void edge_agg4(
    const unsigned short* __restrict__ xl, const unsigned short* __restrict__ xr,
    const float* __restrict__ att, const float* __restrict__ bias,
    const int* __restrict__ rowstart, const int* __restrict__ csr,
    const int* __restrict__ perm,
    unsigned short* __restrict__ out, int N) {
  int wave = threadIdx.x >> 6, lane = threadIdx.x & 63;
  int gid = blockIdx.x * 4 + wave;
  if (gid >= N) return;
  int node = perm[gid];

  float attv[4];
  {
    f32x4 a4 = *reinterpret_cast<const f32x4*>(att + lane * 4);
    #pragma unroll
    for (int j = 0; j < 4; ++j) attv[j] = a4[j] * LOG2E;
  }
  float xrv[4];
  {
    u16x4v r4 = *reinterpret_cast<const u16x4v*>(xr + (size_t)node * 256 + lane * 4);
    #pragma unroll
    for (int j = 0; j < 4; ++j) xrv[j] = bf2f(r4[j]);
  }

  int s0 = rowstart[node], s1 = rowstart[node + 1];
  int end = s1 + (SELF ? 1 : 0);

  // two partial chains halve the serial FMA dependency
  auto score4 = [&](const float* xv) -> float {
    float t0 = xv[0] + xrv[0]; t0 = fmaxf(t0, 0.2f * t0);
    float t1 = xv[1] + xrv[1]; t1 = fmaxf(t1, 0.2f * t1);
    float t2 = xv[2] + xrv[2]; t2 = fmaxf(t2, 0.2f * t2);
    float t3 = xv[3] + xrv[3]; t3 = fmaxf(t3, 0.2f * t3);
    float pa = t0 * attv[0];
    float pb = t1 * attv[1];
    pa = fmaf(t2, attv[2], pa);
    pb = fmaf(t3, attv[3], pb);
    return row16_sum(pa + pb);
  };
  auto loadx = [&](int s, float* xv) {
    u16x4v r = *reinterpret_cast<const u16x4v*>(xl + (size_t)s * 256 + lane * 4);
    #pragma unroll
    for (int j = 0; j < 4; ++j) xv[j] = bf2f(r[j]);
  };

  float m = 0.f, l = 0.f;
  float acc[4] = {0.f, 0.f, 0.f, 0.f};

  int i = s0;
  if (i < end) {           // first edge: m := its score, w == 1
    int s = (i < s1) ? csr[i] : node;
    float xv[4];
    loadx(s, xv);
    m = score4(xv);
    l = 1.f;
    #pragma unroll
    for (int j = 0; j < 4; ++j) acc[j] = xv[j];
    ++i;
  }
  for (; i + 4 <= end; i += 4) {
    int iu = __builtin_amdgcn_readfirstlane(i);   // uniform -> s_load csr
    int s_[4];
    float x_[4][4], p_[4], w_[4];
    #pragma unroll
    for (int q = 0; q < 4; ++q) s_[q] = (iu + q < s1) ? csr[iu + q] : node;
    #pragma unroll
    for (int q = 0; q < 4; ++q) loadx(s_[q], x_[q]);
    #pragma unroll
    for (int q = 0; q < 4; ++q) p_[q] = score4(x_[q]);
    float mx = fmaxf(fmaxf(p_[0], p_[1]), fmaxf(p_[2], p_[3]));
    if (__any(mx > m + THR2)) {
      float mn = fmaxf(m, mx);
      float sc = __builtin_amdgcn_exp2f(m - mn);
      l *= sc;
      #pragma unroll
      for (int j = 0; j < 4; ++j) acc[j] *= sc;
      m = mn;
    }
    #pragma unroll
    for (int q = 0; q < 4; ++q) w_[q] = __builtin_amdgcn_exp2f(p_[q] - m);
    l += (w_[0] + w_[1]) + (w_[2] + w_[3]);
    #pragma unroll
    for (int j = 0; j < 4; ++j)
      acc[j] = fmaf(w_[0], x_[0][j],
               fmaf(w_[1], x_[1][j],
               fmaf(w_[2], x_[2][j],
               fmaf(w_[3], x_[3][j], acc[j]))));
  }
  for (; i < end; ++i) {
    int s = (i < s1) ? csr[i] : node;
    float xv[4];
    loadx(s, xv);
    float p = score4(xv);
    if (__any(p > m + THR2)) {
      float mn = fmaxf(m, p);
      float sc = __builtin_amdgcn_exp2f(m - mn);
      l *= sc;
      #pragma unroll
      for (int j = 0; j < 4; ++j) acc[j] *= sc;
      m = mn;
    }
    float w = __builtin_amdgcn_exp2f(p - m);
    l += w;
    #pragma unroll
    for (int j = 0; j < 4; ++j) acc[j] = fmaf(w, xv[j], acc[j]);
  }

  float rec = 1.f / (l + 1e-16f);
  f32x4 b4 = *reinterpret_cast<const f32x4*>(bias + lane * 4);
  u16x4v w4;
  #pragma unroll
  for (int j = 0; j < 4; ++j) {
    float o = fmaf(acc[j], rec, b4[j]);
    if (RELU) o = fmaxf(o, 0.f);
    w4[j] = f2bf(o);
  }
  *reinterpret_cast<u16x4v*>(out + (size_t)node * 256 + lane * 4) = w4;
}

// H=1: one wave per dst node; r7 structure (4-deep), exp2 domain.
template<bool SELF, bool RELU>
__global__ __launch_bounds__(256) void edge_agg1(
    const unsigned short* __restrict__ xl, const unsigned short* __restrict__ xr,
    const float* __restrict__ att, const float* __restrict__ bias,
    const int* __restrict__ rowstart, const int* __restrict__ csr,
    const int* __restrict__ perm,
    unsigned short* __restrict__ out, int N) {
  int wave = threadIdx.x >> 6, lane = threadIdx.x & 63;
  int gid = blockIdx.x * 4 + wave;
  if (gid >= N) return;
  int node = perm[gid];

  float attv = att[lane] * LOG2E;
  float xrv = bf2f(xr[(size_t)node * 64 + lane]);

  int s0 = rowstart[node], s1 = rowstart[node + 1];
  int end = s1 + (SELF ? 1 : 0);

  auto score = [&](float xv) {
    float tv = xv + xrv;
    tv = fmaxf(tv, 0.2f * tv);
    float p = row16_sum(tv * attv);
    p += __shfl_xor(p, 16);
    p += __shfl_xor(p, 32);
    return p;
  };

  float m = 0.f, l = 0.f, acc = 0.f;

  int i = s0;
  if (i < end) {
    int s = (i < s1) ? csr[i] : node;
    float xv = bf2f(xl[(size_t)s * 64 + lane]);
    m = score(xv);
    l = 1.f;
    acc = xv;
    ++i;
  }
  for (; i + 4 <= end; i += 4) {
    int iu = __builtin_amdgcn_readfirstlane(i);
    int s_[4];
    float x_[4], p_[4], w_[4];
    #pragma unroll
    for (int q = 0; q < 4; ++q) s_[q] = (iu + q < s1) ? csr[iu + q] : node;
    #pragma unroll
    for (int q = 0; q < 4; ++q) x_[q] = bf2f(xl[(size_t)s_[q] * 64 + lane]);
    #pragma unroll
    for (int q = 0; q < 4; ++q) p_[q] = score(x_[q]);
    float mx = fmaxf(fmaxf(p_[0], p_[1]), fmaxf(p_[2], p_[3]));
    if (__any(mx > m + THR2)) {
      float mn = fmaxf(m, mx);
      float sc = __builtin_amdgcn_exp2f(m - mn);
      l *= sc; acc *= sc; m = mn;
    }
    #pragma unroll
    for (int q = 0; q < 4; ++q) w_[q] = __builtin_amdgcn_exp2f(p_[q] - m);
    l += (w_[0] + w_[1]) + (w_[2] + w_[3]);
    acc = fmaf(w_[0], x_[0], fmaf(w_[1], x_[1], fmaf(w_[2], x_[2], fmaf(w_[3], x_[3], acc))));
  }
  for (; i < end; ++i) {
    int s = (i < s1) ? csr[i] : node;
    float xv = bf2f(xl[(size_t)s * 64 + lane]);
    float p = score(xv);
    if (__any(p > m + THR2)) {
      float mn = fmaxf(m, p);
      float sc = __builtin_amdgcn_exp2f(m - mn);
      l *= sc; acc *= sc; m = mn;
    }
    float w = __builtin_amdgcn_exp2f(p - m);
    l += w;
    acc = fmaf(w, xv, acc);
  }

  float rec = 1.f / (l + 1e-16f);
  float o = fmaf(acc, rec, bias[lane]);
  if (RELU) o = fmaxf(o, 0.f);
  out[(size_t)node * 64 + lane] = f2bf(o);
}

// ---------------- fused mean-pool + MLP + softmax: one block per graph ----------------
__global__ __launch_bounds__(256) void pool_mlp(
    const unsigned short* __restrict__ h, const int* __restrict__ batch,
    const float* __restrict__ w1, const float* __restrict__ b1,
    const float* __restrict__ w2, const float* __restrict__ b2,
    const float* __restrict__ w3, const float* __restrict__ b3,
    float* __restrict__ out, int N) {
  int g = blockIdx.x;
  int lo = 0, hi = N;
  while (lo < hi) { int mid = (lo + hi) >> 1; if (batch[mid] < g) lo = mid + 1; else hi = mid; }
  int n0 = lo;
  hi = N;
  while (lo < hi) { int mid = (lo + hi) >> 1; if (batch[mid] < g + 1) lo = mid + 1; else hi = mid; }
  int n1 = lo;

  int t = threadIdx.x;
  int c2 = t & 31, r = t >> 5;
  float ax = 0.f, ay = 0.f;
  for (int n = n0 + r; n < n1; n += 8) {
    unsigned int u = *reinterpret_cast<const unsigned int*>(h + (size_t)n * 64 + c2 * 2);
    ax += bf2f((unsigned short)(u & 0xffffu));
    ay += bf2f((unsigned short)(u >> 16));
  }
  __shared__ float redx[8][32], redy[8][32];
  __shared__ float sh[64];
  redx[r][c2] = ax; redy[r][c2] = ay;
  __syncthreads();
  if (t < 64) {
    int lane = t;
    float s = 0.f;
    #pragma unroll
    for (int q = 0; q < 8; ++q) s += (lane & 1) ? redy[q][lane >> 1] : redx[q][lane >> 1];
    float cnt = fmaxf((float)(n1 - n0), 1.f);
    sh[lane] = s / cnt;
    float h1 = b1[lane];
    for (int k = 0; k < 64; ++k) h1 = fmaf(sh[k], w1[k * 64 + lane], h1);
    h1 = fmaxf(h1, 0.f);
    sh[lane] = h1;
    float h2 = b2[lane];
    for (int k = 0; k < 64; ++k) h2 = fmaf(sh[k], w2[k * 64 + lane], h2);
    h2 = fmaxf(h2, 0.f);
    sh[lane] = h2;
    float lg = -INFINITY;
    if (lane < 12) {
      lg = b3[lane];
      for (int k = 0; k < 64; ++k) lg = fmaf(sh[k], w3[k * 12 + lane], lg);
    }
    float mx = lg;
    #pragma unroll
    for (int msk = 1; msk < 64; msk <<= 1) mx = fmaxf(mx, __shfl_xor(mx, msk));
    float ex = (lane < 12) ? __expf(lg - mx) : 0.f;
    float sm = ex;
    #pragma unroll
    for (int msk = 1; msk < 64; msk <<= 1) sm += __shfl_xor(sm, msk);
    if (lane < 12) out[(size_t)g * 12 + lane] = ex / sm;
  }
}

// ---------------- host ----------------
extern "C" void kernel_launch(void* const* d_in, const int* in_sizes, int n_in,
                              void* d_out, int out_size, void* d_ws, size_t ws_size,
                              hipStream_t stream) {
  const float* x    = (const float*)d_in[0];
  const int* edge   = (const int*)d_in[1];
  const int* batch  = (const int*)d_in[2];
  const float* W1l  = (const float*)d_in[3];
  const float* W1r  = (const float*)d_in[4];
  const float* a1   = (const float*)d_in[5];
  const float* b1   = (const float*)d_in[6];
  const float* W2l  = (const float*)d_in[7];
  const float* W2r  = (const float*)d_in[8];
  const float* a2   = (const float*)d_in[9];
  const float* b2   = (const float*)d_in[10];
  const float* W3l  = (const float*)d_in[11];
  const float* W3r  = (const float*)d_in[12];
  const float* a3   = (const float*)d_in[13];
  const float* b3   = (const float*)d_in[14];
  const float* lw1  = (const float*)d_in[15];
  const float* lb1  = (const float*)d_in[16];
  const float* lw2  = (const float*)d_in[17];
  const float* lb2  = (const float*)d_in[18];
  const float* lw3  = (const float*)d_in[19];
  const float* lb3  = (const float*)d_in[20];

  const int E = in_sizes[1] / 2;
  const int N = in_sizes[2];
  const int F0 = in_sizes[0] / N;   // 128
  const int G = out_size / 12;      // 512
  const int* src = edge;
  const int* dst = edge + E;

  const int gx = (N + 127) / 128;
  const int Mpad = gx * 128;
  const int nb = (N + 255) / 256;

  // workspace carve (256B aligned)
  char* p = (char*)d_ws;
  auto alloc = [&](size_t bytes) { char* q = p; p += (bytes + 255) & ~(size_t)255; return q; };
  unsigned short* bufA = (unsigned short*)alloc((size_t)Mpad * 256 * 2);
  unsigned short* bufB = (unsigned short*)alloc((size_t)Mpad * 256 * 2);
  unsigned short* bufH = (unsigned short*)alloc((size_t)Mpad * 256 * 2);
  unsigned short* xbf  = (unsigned short*)alloc((size_t)Mpad * 128 * 2);
  unsigned short* Wt1L = (unsigned short*)alloc(128 * 256 * 2);
  unsigned short* Wt1R = (unsigned short*)alloc(128 * 256 * 2);
  unsigned short* Wt2L = (unsigned short*)alloc(256 * 256 * 2);
  unsigned short* Wt2R = (unsigned short*)alloc(256 * 256 * 2);
  unsigned short* Wt3L = (unsigned short*)alloc(256 * 64 * 2);
  unsigned short* Wt3R = (unsigned short*)alloc(256 * 64 * 2);
  int* counts    = (int*)alloc((size_t)N * 4);      // contiguous with binTotal for one memset
  int* binTotal  = (int*)alloc(256 * 4);
  int* binStart  = (int*)alloc(256 * 4);
  int* blockBase = (int*)alloc((size_t)nb * 256 * 4);
  int* rowstart  = (int*)alloc((size_t)(N + 1) * 4);
  int* cursor    = (int*)alloc((size_t)N * 4);
  int* perm      = (int*)alloc((size_t)N * 4);
  int* bsums     = (int*)alloc(4096 * 4);
  int* boffs     = (int*)alloc(4096 * 4);
  int* csr       = (int*)alloc((size_t)E * 4);

  // ---- CSR by dst + LPT perm (folded) ----
  size_t countsPad = ((size_t)N * 4 + 255) & ~(size_t)255;
  hipMemsetAsync(counts, 0, countsPad + 256 * 4, stream);
  hist_kernel<<<(E + 255) / 256, 256, 0, stream>>>(dst, counts, E);
  scan_block_deg<<<nb, 256, 0, stream>>>(counts, rowstart, bsums, binTotal, blockBase, N);
  scan2_offsets<<<1, 256, 0, stream>>>(bsums, boffs, binTotal, binStart, nb);
  scan_add_place<<<nb, 256, 0, stream>>>(rowstart, boffs, cursor, counts, binStart, blockBase, perm, N, E);
  scatter_kernel<<<(E + 255) / 256, 256, 0, stream>>>(src, dst, cursor, csr, E);

  // ---- weight transposes + x conversion ----
  {
    WPack wp;
    const float* ins[6] = {W1l, W1r, W2l, W2r, W3l, W3r};
    unsigned short* outs[6] = {Wt1L, Wt1R, Wt2L, Wt2R, Wt3L, Wt3R};
    int Ks[6] = {F0, F0, 256, 256, 256, 256};
    int Ns[6] = {256, 256, 256, 256, 64, 64};
    int acc0 = 0;
    for (int s = 0; s < 6; ++s) {
      wp.in[s] = ins[s]; wp.out[s] = outs[s]; wp.K[s] = Ks[s]; wp.Ncol[s] = Ns[s];
      wp.start[s] = acc0; acc0 += Ks[s] * Ns[s];
    }
    wp.start[6] = acc0;
    convert_all<<<(acc0 + 255) / 256, 256, 0, stream>>>(wp);
  }
  {
    int n4 = (N * F0) / 4;
    convert_x<<<(n4 + 255) / 256, 256, 0, stream>>>(x, xbf, n4);
  }

  int ne = (N + 3) / 4;

  // ---- conv1: K=128, Ncol=256, no self loops, relu; A = xbf (bf16, GLL) ----
  gemm_dual<128, 2, 2><<<dim3(gx, 2, 2), 256, 0, stream>>>(xbf, Wt1L, Wt1R, bufA, bufB, N, F0, 256);
  edge_agg4<false, true><<<ne, 256, 0, stream>>>(bufA, bufB, a1, b1, rowstart, csr, perm, bufH, N);

  // ---- conv2: K=256, Ncol=256, self loops, relu ----
  gemm_dual<128, 2, 2><<<dim3(gx, 2, 2), 256, 0, stream>>>(bufH, Wt2L, Wt2R, bufA, bufB, N, 256, 256);
  edge_agg4<true, true><<<ne, 256, 0, stream>>>(bufA, bufB, a2, b2, rowstart, csr, perm, bufH, N);

  // ---- conv3: K=256, Ncol=64, self loops, no relu ----
  gemm_dual<64, 4, 1><<<dim3(gx, 1, 2), 256, 0, stream>>>(bufH, Wt3L, Wt3R, bufA, bufB, N, 256, 64);
  edge_agg1<true, false><<<ne, 256, 0, stream>>>(bufA, bufB, a3, b3, rowstart, csr, perm, bufH, N);

  // ---- fused mean pool + MLP head + softmax ----
  pool_mlp<<<G, 256, 0, stream>>>(bufH, batch, lw1, lb1, lw2, lb2, lw3, lb3,
                                  (float*)d_out, N);
}

// Round 11
// 447.223 us; speedup vs baseline: 1.0737x; 1.0304x over previous
//
#include <hip/hip_runtime.h>
#include <hip/hip_bf16.h>
#include <cstdint>
#include <cstddef>

typedef short bf16x8 __attribute__((ext_vector_type(8)));
typedef float f32x4 __attribute__((ext_vector_type(4)));
typedef unsigned short u16x4v __attribute__((ext_vector_type(4)));

__device__ __forceinline__ float bf2f(unsigned short u) {
  union { unsigned int u; float f; } v; v.u = ((unsigned int)u) << 16; return v.f;
}
__device__ __forceinline__ unsigned short f2bf(float f) {
  union { float f; unsigned int u; } v; v.f = f;
  unsigned int r = v.u + 0x7fffu + ((v.u >> 16) & 1u);
  return (unsigned short)(r >> 16);
}
// async global->LDS, 16B per lane
__device__ __forceinline__ void gll16(const void* g, void* l) {
  __builtin_amdgcn_global_load_lds(
      (const __attribute__((address_space(1))) unsigned int*)g,
      (__attribute__((address_space(3))) unsigned int*)l, 16, 0, 0);
}
// DPP rotate-within-row16 + add
template<int CTRL>
__device__ __forceinline__ float dpp_ror_add(float p) {
  int t = __builtin_amdgcn_update_dpp(0, __builtin_bit_cast(int, p), CTRL, 0xf, 0xf, true);
  return p + __builtin_bit_cast(float, t);
}
__device__ __forceinline__ float row16_sum(float p) {
  p = dpp_ror_add<0x121>(p);
  p = dpp_ror_add<0x122>(p);
  p = dpp_ror_add<0x124>(p);
  p = dpp_ror_add<0x128>(p);
  return p;
}

#define LOG2E 1.44269504088896f
#define THR2  11.5415603271f     // 8 * log2(e)

// ---------------- weight transpose+convert (into concatenated L||R layouts) ----------------
struct WPack {
  const float* in[6];
  unsigned short* out[6];
  int K[6], Ncol[6];
  int start[7];
};
__global__ __launch_bounds__(256) void convert_all(WPack p) {
  int idx = blockIdx.x * 256 + threadIdx.x;
  #pragma unroll
  for (int s = 0; s < 6; ++s) {
    if (idx >= p.start[s] && idx < p.start[s + 1]) {
      int lidx = idx - p.start[s];
      int k = lidx / p.Ncol[s], n = lidx % p.Ncol[s];
      p.out[s][n * p.K[s] + k] = f2bf(p.in[s][lidx]);
    }
  }
}

// x (f32) -> bf16, vectorized 4-wide
__global__ __launch_bounds__(256) void convert_x(const float* __restrict__ in,
                                                 unsigned short* __restrict__ out, int n4) {
  int i = blockIdx.x * 256 + threadIdx.x;
  if (i < n4) {
    f32x4 v = *reinterpret_cast<const f32x4*>(in + (size_t)i * 4);
    u16x4v o;
    #pragma unroll
    for (int j = 0; j < 4; ++j) o[j] = f2bf(v[j]);
    *reinterpret_cast<u16x4v*>(out + (size_t)i * 4) = o;
  }
}

// ---------------- GEMM on concatenated weights: 8 waves, 128xBN tile ----------------
// Wt is [BNtot][K] with cols [0,NL) -> outL, [NL,2NL) -> outR.
template<int BN, int NL>
__global__ __launch_bounds__(512) void gemm_cat(
    const unsigned short* __restrict__ A,
    const unsigned short* __restrict__ Wt,
    unsigned short* __restrict__ outL, unsigned short* __restrict__ outR,
    int M, int K) {
  constexpr int BM = 128, BK = 64;
  constexpr int WAVES_M = 2, WAVES_N = 4;
  constexpr int WTM = BM / WAVES_M;       // 64
  constexpr int WTN = BN / WAVES_N;       // 64 (BN=256) / 32 (BN=128)
  constexpr int MR = WTM / 16;            // 4
  constexpr int NR = WTN / 16;            // 4 / 2

  __shared__ alignas(16) unsigned short lAt[BM * BK];
  __shared__ alignas(16) unsigned short lBt[BN * BK];

  int t = threadIdx.x;
  int lane = t & 63, wid = t >> 6;        // 0..7
  int wm = wid / WAVES_N, wn = wid % WAVES_N;
  int rowBase = blockIdx.x * BM;
  int colBase = blockIdx.y * BN;

  f32x4 acc[MR][NR] = {};

  for (int k0 = 0; k0 < K; k0 += BK) {
    #pragma unroll
    for (int p = 0; p < BM / 64; ++p) {   // 2 chunks/wave
      int chunk = wid * (BM / 64) + p;
      int row = chunk * 8 + (lane >> 3);
      int c = (lane & 7) ^ (row & 7);     // pre-swizzled source, linear LDS dest
      gll16(A + (size_t)(rowBase + row) * K + k0 + c * 8, &lAt[chunk * 512]);
    }
    #pragma unroll
    for (int p = 0; p < BN / 64; ++p) {   // 4 / 2 chunks/wave
      int chunk = wid * (BN / 64) + p;
      int row = chunk * 8 + (lane >> 3);
      int c = (lane & 7) ^ (row & 7);
      gll16(Wt + (size_t)(colBase + row) * K + k0 + c * 8, &lBt[chunk * 512]);
    }
    __syncthreads();
    #pragma unroll
    for (int kk = 0; kk < 2; ++kk) {
      bf16x8 af[MR], bfr[NR];
      int cidx = kk * 4 + (lane >> 4);
      #pragma unroll
      for (int mi = 0; mi < MR; ++mi) {
        int row = wm * WTM + mi * 16 + (lane & 15);
        af[mi] = *reinterpret_cast<const bf16x8*>(&lAt[row * 64 + ((cidx ^ (row & 7)) * 8)]);
      }
      #pragma unroll
      for (int ni = 0; ni < NR; ++ni) {
        int row = wn * WTN + ni * 16 + (lane & 15);
        bfr[ni] = *reinterpret_cast<const bf16x8*>(&lBt[row * 64 + ((cidx ^ (row & 7)) * 8)]);
      }
      #pragma unroll
      for (int mi = 0; mi < MR; ++mi)
        #pragma unroll
        for (int ni = 0; ni < NR; ++ni)
          acc[mi][ni] = __builtin_amdgcn_mfma_f32_16x16x32_bf16(af[mi], bfr[ni], acc[mi][ni], 0, 0, 0);
    }
    __syncthreads();
  }
  #pragma unroll
  for (int mi = 0; mi < MR; ++mi)
    #pragma unroll
    for (int ni = 0; ni < NR; ++ni) {
      int col = colBase + wn * WTN + ni * 16 + (lane & 15);
      unsigned short* op = (col < NL) ? (outL + col) : (outR + (col - NL));
      #pragma unroll
      for (int r = 0; r < 4; ++r) {
        int row = rowBase + wm * WTM + mi * 16 + (lane >> 4) * 4 + r;
        if (row < M) op[(size_t)row * NL] = f2bf(acc[mi][ni][r]);
      }
    }
}

// ---------------- CSR build (+ LPT folded in) ----------------
__global__ __launch_bounds__(256) void hist_kernel(const int* __restrict__ dst, int* __restrict__ counts, int E) {
  int e = blockIdx.x * 256 + threadIdx.x;
  if (e < E) atomicAdd(&counts[dst[e]], 1);
}

__global__ __launch_bounds__(256) void scan_block_deg(
    const int* __restrict__ in, int* __restrict__ out, int* __restrict__ sums,
    int* __restrict__ binTotal, int* __restrict__ blockBase, int n) {
  __shared__ int lh[256];
  __shared__ int wsum[4];
  lh[threadIdx.x] = 0;
  __syncthreads();
  int i = blockIdx.x * 256 + threadIdx.x;
  int lane = threadIdx.x & 63, wid = threadIdx.x >> 6;
  int v = (i < n) ? in[i] : 0;
  if (i < n) atomicAdd(&lh[v < 255 ? v : 255], 1);
  int s = v;
  #pragma unroll
  for (int d = 1; d < 64; d <<= 1) { int tt = __shfl_up(s, d); if (lane >= d) s += tt; }
  if (lane == 63) wsum[wid] = s;
  __syncthreads();
  int off = 0;
  for (int w = 0; w < wid; ++w) off += wsum[w];
  if (i < n) out[i] = off + s - v;
  if (threadIdx.x == 255) sums[blockIdx.x] = off + s;
  int c = lh[threadIdx.x];
  blockBase[blockIdx.x * 256 + threadIdx.x] = c ? atomicAdd(&binTotal[threadIdx.x], c) : 0;
}

__global__ __launch_bounds__(256) void scan2_offsets(
    const int* __restrict__ bsums, int* __restrict__ boffs,
    const int* __restrict__ binTotal, int* __restrict__ binStart, int n) {
  __shared__ int ws[4];
  int t = threadIdx.x;
  int lane = t & 63, w = t >> 6;
  {
    int v = (t < n) ? bsums[t] : 0;
    int s = v;
    #pragma unroll
    for (int d = 1; d < 64; d <<= 1) { int tt = __shfl_up(s, d); if (lane >= d) s += tt; }
    if (lane == 63) ws[w] = s;
    __syncthreads();
    int off = 0;
    for (int u = 0; u < w; ++u) off += ws[u];
    if (t < n) boffs[t] = off + s - v;
    __syncthreads();
  }
  {
    int v = binTotal[255 - t];
    int s = v;
    #pragma unroll
    for (int d = 1; d < 64; d <<= 1) { int tt = __shfl_up(s, d); if (lane >= d) s += tt; }
    if (lane == 63) ws[w] = s;
    __syncthreads();
    int off = 0;
    for (int u = 0; u < w; ++u) off += ws[u];
    binStart[255 - t] = off + s - v;
  }
}

__global__ __launch_bounds__(256) void scan_add_place(
    int* __restrict__ rs, const int* __restrict__ boffs, int* __restrict__ cursor,
    const int* __restrict__ counts, const int* __restrict__ binStart,
    const int* __restrict__ blockBase, int* __restrict__ perm, int n, int E) {
  __shared__ int lcur[256];
  lcur[threadIdx.x] = binStart[threadIdx.x] + blockBase[blockIdx.x * 256 + threadIdx.x];
  __syncthreads();
  int i = blockIdx.x * 256 + threadIdx.x;
  if (i < n) {
    int v = rs[i] + boffs[blockIdx.x];
    rs[i] = v;
    cursor[i] = v;
    int d = counts[i]; if (d > 255) d = 255;
    perm[atomicAdd(&lcur[d], 1)] = i;
  }
  if (i == 0) rs[n] = E;
}

__global__ __launch_bounds__(256) void scatter_kernel(const int* __restrict__ src, const int* __restrict__ dst,
                                                      int* __restrict__ cursor, int* __restrict__ csr, int E) {
  int e = blockIdx.x * 256 + threadIdx.x;
  if (e < E) {
    int p = atomicAdd(&cursor[dst[e]], 1);
    csr[p] = src[e];
  }
}

// ---------------- edge aggregation (FROZEN r10 structure: VALU floor) ----------------
// H=4: one wave per dst node, LPT order via perm; 4-deep unroll.
template<bool SELF, bool RELU>
__global__ __launch_bounds__(256) void edge_agg4(
    const unsigned short* __restrict__ xl, const unsigned short* __restrict__ xr,
    const float* __restrict__ att, const float* __restrict__ bias,
    const int* __restrict__ rowstart, const int* __restrict__ csr,
    const int* __restrict__ perm,
    unsigned short* __restrict__ out, int N) {
  int wave = threadIdx.x >> 6, lane = threadIdx.x & 63;
  int gid = blockIdx.x * 4 + wave;
  if (gid >= N) return;
  int node = perm[gid];

  float attv[4];
  {
    f32x4 a4 = *reinterpret_cast<const f32x4*>(att + lane * 4);
    #pragma unroll
    for (int j = 0; j < 4; ++j) attv[j] = a4[j] * LOG2E;
  }
  float xrv[4];
  {
    u16x4v r4 = *reinterpret_cast<const u16x4v*>(xr + (size_t)node * 256 + lane * 4);
    #pragma unroll
    for (int j = 0; j < 4; ++j) xrv[j] = bf2f(r4[j]);
  }

  int s0 = rowstart[node], s1 = rowstart[node + 1];
  int end = s1 + (SELF ? 1 : 0);

  auto score4 = [&](const float* xv) -> float {
    float t0 = xv[0] + xrv[0]; t0 = fmaxf(t0, 0.2f * t0);
    float t1 = xv[1] + xrv[1]; t1 = fmaxf(t1, 0.2f * t1);
    float t2 = xv[2] + xrv[2]; t2 = fmaxf(t2, 0.2f * t2);
    float t3 = xv[3] + xrv[3]; t3 = fmaxf(t3, 0.2f * t3);
    float pa = t0 * attv[0];
    float pb = t1 * attv[1];
    pa = fmaf(t2, attv[2], pa);
    pb = fmaf(t3, attv[3], pb);
    return row16_sum(pa + pb);
  };
  auto loadx = [&](int s, float* xv) {
    u16x4v r = *reinterpret_cast<const u16x4v*>(xl + (size_t)s * 256 + lane * 4);
    #pragma unroll
    for (int j = 0; j < 4; ++j) xv[j] = bf2f(r[j]);
  };

  float m = 0.f, l = 0.f;
  float acc[4] = {0.f, 0.f, 0.f, 0.f};

  int i = s0;
  if (i < end) {
    int s = (i < s1) ? csr[i] : node;
    float xv[4];
    loadx(s, xv);
    m = score4(xv);
    l = 1.f;
    #pragma unroll
    for (int j = 0; j < 4; ++j) acc[j] = xv[j];
    ++i;
  }
  for (; i + 4 <= end; i += 4) {
    int iu = __builtin_amdgcn_readfirstlane(i);
    int s_[4];
    float x_[4][4], p_[4], w_[4];
    #pragma unroll
    for (int q = 0; q < 4; ++q) s_[q] = (iu + q < s1) ? csr[iu + q] : node;
    #pragma unroll
    for (int q = 0; q < 4; ++q) loadx(s_[q], x_[q]);
    #pragma unroll
    for (int q = 0; q < 4; ++q) p_[q] = score4(x_[q]);
    float mx = fmaxf(fmaxf(p_[0], p_[1]), fmaxf(p_[2], p_[3]));
    if (__any(mx > m + THR2)) {
      float mn = fmaxf(m, mx);
      float sc = __builtin_amdgcn_exp2f(m - mn);
      l *= sc;
      #pragma unroll
      for (int j = 0; j < 4; ++j) acc[j] *= sc;
      m = mn;
    }
    #pragma unroll
    for (int q = 0; q < 4; ++q) w_[q] = __builtin_amdgcn_exp2f(p_[q] - m);
    l += (w_[0] + w_[1]) + (w_[2] + w_[3]);
    #pragma unroll
    for (int j = 0; j < 4; ++j)
      acc[j] = fmaf(w_[0], x_[0][j],
               fmaf(w_[1], x_[1][j],
               fmaf(w_[2], x_[2][j],
               fmaf(w_[3], x_[3][j], acc[j]))));
  }
  for (; i < end; ++i) {
    int s = (i < s1) ? csr[i] : node;
    float xv[4];
    loadx(s, xv);
    float p = score4(xv);
    if (__any(p > m + THR2)) {
      float mn = fmaxf(m, p);
      float sc = __builtin_amdgcn_exp2f(m - mn);
      l *= sc;
      #pragma unroll
      for (int j = 0; j < 4; ++j) acc[j] *= sc;
      m = mn;
    }
    float w = __builtin_amdgcn_exp2f(p - m);
    l += w;
    #pragma unroll
    for (int j = 0; j < 4; ++j) acc[j] = fmaf(w, xv[j], acc[j]);
  }

  float rec = 1.f / (l + 1e-16f);
  f32x4 b4 = *reinterpret_cast<const f32x4*>(bias + lane * 4);
  u16x4v w4;
  #pragma unroll
  for (int j = 0; j < 4; ++j) {
    float o = fmaf(acc[j], rec, b4[j]);
    if (RELU) o = fmaxf(o, 0.f);
    w4[j] = f2bf(o);
  }
  *reinterpret_cast<u16x4v*>(out + (size_t)node * 256 + lane * 4) = w4;
}

// H=1: one wave per dst node; r10 structure.
template<bool SELF, bool RELU>
__global__ __launch_bounds__(256) void edge_agg1(
    const unsigned short* __restrict__ xl, const unsigned short* __restrict__ xr,
    const float* __restrict__ att, const float* __restrict__ bias,
    const int* __restrict__ rowstart, const int* __restrict__ csr,
    const int* __restrict__ perm,
    unsigned short* __restrict__ out, int N) {
  int wave = threadIdx.x >> 6, lane = threadIdx.x & 63;
  int gid = blockIdx.x * 4 + wave;
  if (gid >= N) return;
  int node = perm[gid];

  float attv = att[lane] * LOG2E;
  float xrv = bf2f(xr[(size_t)node * 64 + lane]);

  int s0 = rowstart[node], s1 = rowstart[node + 1];
  int end = s1 + (SELF ? 1 : 0);

  auto score = [&](float xv) {
    float tv = xv + xrv;
    tv = fmaxf(tv, 0.2f * tv);
    float p = row16_sum(tv * attv);
    p += __shfl_xor(p, 16);
    p += __shfl_xor(p, 32);
    return p;
  };

  float m = 0.f, l = 0.f, acc = 0.f;

  int i = s0;
  if (i < end) {
    int s = (i < s1) ? csr[i] : node;
    float xv = bf2f(xl[(size_t)s * 64 + lane]);
    m = score(xv);
    l = 1.f;
    acc = xv;
    ++i;
  }
  for (; i + 4 <= end; i += 4) {
    int iu = __builtin_amdgcn_readfirstlane(i);
    int s_[4];
    float x_[4], p_[4], w_[4];
    #pragma unroll
    for (int q = 0; q < 4; ++q) s_[q] = (iu + q < s1) ? csr[iu + q] : node;
    #pragma unroll
    for (int q = 0; q < 4; ++q) x_[q] = bf2f(xl[(size_t)s_[q] * 64 + lane]);
    #pragma unroll
    for (int q = 0; q < 4; ++q) p_[q] = score(x_[q]);
    float mx = fmaxf(fmaxf(p_[0], p_[1]), fmaxf(p_[2], p_[3]));
    if (__any(mx > m + THR2)) {
      float mn = fmaxf(m, mx);
      float sc = __builtin_amdgcn_exp2f(m - mn);
      l *= sc; acc *= sc; m = mn;
    }
    #pragma unroll
    for (int q = 0; q < 4; ++q) w_[q] = __builtin_amdgcn_exp2f(p_[q] - m);
    l += (w_[0] + w_[1]) + (w_[2] + w_[3]);
    acc = fmaf(w_[0], x_[0], fmaf(w_[1], x_[1], fmaf(w_[2], x_[2], fmaf(w_[3], x_[3], acc))));
  }
  for (; i < end; ++i) {
    int s = (i < s1) ? csr[i] : node;
    float xv = bf2f(xl[(size_t)s * 64 + lane]);
    float p = score(xv);
    if (__any(p > m + THR2)) {
      float mn = fmaxf(m, p);
      float sc = __builtin_amdgcn_exp2f(m - mn);
      l *= sc; acc *= sc; m = mn;
    }
    float w = __builtin_amdgcn_exp2f(p - m);
    l += w;
    acc = fmaf(w, xv, acc);
  }

  float rec = 1.f / (l + 1e-16f);
  float o = fmaf(acc, rec, bias[lane]);
  if (RELU) o = fmaxf(o, 0.f);
  out[(size_t)node * 64 + lane] = f2bf(o);
}

// ---------------- fused mean-pool + MLP + softmax: one block per graph ----------------
__global__ __launch_bounds__(256) void pool_mlp(
    const unsigned short* __restrict__ h, const int* __restrict__ batch,
    const float* __restrict__ w1, const float* __restrict__ b1,
    const float* __restrict__ w2, const float* __restrict__ b2,
    const float* __restrict__ w3, const float* __restrict__ b3,
    float* __restrict__ out, int N) {
  int g = blockIdx.x;
  int lo = 0, hi = N;
  while (lo < hi) { int mid = (lo + hi) >> 1; if (batch[mid] < g) lo = mid + 1; else hi = mid; }
  int n0 = lo;
  hi = N;
  while (lo < hi) { int mid = (lo + hi) >> 1; if (batch[mid] < g + 1) lo = mid + 1; else hi = mid; }
  int n1 = lo;

  int t = threadIdx.x;
  int c2 = t & 31, r = t >> 5;
  float ax = 0.f, ay = 0.f;
  for (int n = n0 + r; n < n1; n += 8) {
    unsigned int u = *reinterpret_cast<const unsigned int*>(h + (size_t)n * 64 + c2 * 2);
    ax += bf2f((unsigned short)(u & 0xffffu));
    ay += bf2f((unsigned short)(u >> 16));
  }
  __shared__ float redx[8][32], redy[8][32];
  __shared__ float sh[64];
  redx[r][c2] = ax; redy[r][c2] = ay;
  __syncthreads();
  if (t < 64) {
    int lane = t;
    float s = 0.f;
    #pragma unroll
    for (int q = 0; q < 8; ++q) s += (lane & 1) ? redy[q][lane >> 1] : redx[q][lane >> 1];
    float cnt = fmaxf((float)(n1 - n0), 1.f);
    sh[lane] = s / cnt;
    float h1 = b1[lane];
    for (int k = 0; k < 64; ++k) h1 = fmaf(sh[k], w1[k * 64 + lane], h1);
    h1 = fmaxf(h1, 0.f);
    sh[lane] = h1;
    float h2 = b2[lane];
    for (int k = 0; k < 64; ++k) h2 = fmaf(sh[k], w2[k * 64 + lane], h2);
    h2 = fmaxf(h2, 0.f);
    sh[lane] = h2;
    float lg = -INFINITY;
    if (lane < 12) {
      lg = b3[lane];
      for (int k = 0; k < 64; ++k) lg = fmaf(sh[k], w3[k * 12 + lane], lg);
    }
    float mx = lg;
    #pragma unroll
    for (int msk = 1; msk < 64; msk <<= 1) mx = fmaxf(mx, __shfl_xor(mx, msk));
    float ex = (lane < 12) ? __expf(lg - mx) : 0.f;
    float sm = ex;
    #pragma unroll
    for (int msk = 1; msk < 64; msk <<= 1) sm += __shfl_xor(sm, msk);
    if (lane < 12) out[(size_t)g * 12 + lane] = ex / sm;
  }
}

// ---------------- host ----------------
extern "C" void kernel_launch(void* const* d_in, const int* in_sizes, int n_in,
                              void* d_out, int out_size, void* d_ws, size_t ws_size,
                              hipStream_t stream) {
  const float* x    = (const float*)d_in[0];
  const int* edge   = (const int*)d_in[1];
  const int* batch  = (const int*)d_in[2];
  const float* W1l  = (const float*)d_in[3];
  const float* W1r  = (const float*)d_in[4];
  const float* a1   = (const float*)d_in[5];
  const float* b1   = (const float*)d_in[6];
  const float* W2l  = (const float*)d_in[7];
  const float* W2r  = (const float*)d_in[8];
  const float* a2   = (const float*)d_in[9];
  const float* b2   = (const float*)d_in[10];
  const float* W3l  = (const float*)d_in[11];
  const float* W3r  = (const float*)d_in[12];
  const float* a3   = (const float*)d_in[13];
  const float* b3   = (const float*)d_in[14];
  const float* lw1  = (const float*)d_in[15];
  const float* lb1  = (const float*)d_in[16];
  const float* lw2  = (const float*)d_in[17];
  const float* lb2  = (const float*)d_in[18];
  const float* lw3  = (const float*)d_in[19];
  const float* lb3  = (const float*)d_in[20];

  const int E = in_sizes[1] / 2;
  const int N = in_sizes[2];
  const int F0 = in_sizes[0] / N;   // 128
  const int G = out_size / 12;      // 512
  const int* src = edge;
  const int* dst = edge + E;

  const int gx = (N + 127) / 128;
  const int Mpad = gx * 128;
  const int nb = (N + 255) / 256;

  // workspace carve (256B aligned)
  char* p = (char*)d_ws;
  auto alloc = [&](size_t bytes) { char* q = p; p += (bytes + 255) & ~(size_t)255; return q; };
  unsigned short* bufA = (unsigned short*)alloc((size_t)Mpad * 256 * 2);
  unsigned short* bufB = (unsigned short*)alloc((size_t)Mpad * 256 * 2);
  unsigned short* bufH = (unsigned short*)alloc((size_t)Mpad * 256 * 2);
  unsigned short* xbf  = (unsigned short*)alloc((size_t)Mpad * 128 * 2);
  unsigned short* Wc1  = (unsigned short*)alloc(512 * 128 * 2);   // [L(256)||R(256)] x K=128
  unsigned short* Wc2  = (unsigned short*)alloc(512 * 256 * 2);   // [256||256] x 256
  unsigned short* Wc3  = (unsigned short*)alloc(128 * 256 * 2);   // [64||64] x 256
  int* counts    = (int*)alloc((size_t)N * 4);      // contiguous with binTotal for one memset
  int* binTotal  = (int*)alloc(256 * 4);
  int* binStart  = (int*)alloc(256 * 4);
  int* blockBase = (int*)alloc((size_t)nb * 256 * 4);
  int* rowstart  = (int*)alloc((size_t)(N + 1) * 4);
  int* cursor    = (int*)alloc((size_t)N * 4);
  int* perm      = (int*)alloc((size_t)N * 4);
  int* bsums     = (int*)alloc(4096 * 4);
  int* boffs     = (int*)alloc(4096 * 4);
  int* csr       = (int*)alloc((size_t)E * 4);

  // ---- CSR by dst + LPT perm (folded) ----
  size_t countsPad = ((size_t)N * 4 + 255) & ~(size_t)255;
  hipMemsetAsync(counts, 0, countsPad + 256 * 4, stream);
  hist_kernel<<<(E + 255) / 256, 256, 0, stream>>>(dst, counts, E);
  scan_block_deg<<<nb, 256, 0, stream>>>(counts, rowstart, bsums, binTotal, blockBase, N);
  scan2_offsets<<<1, 256, 0, stream>>>(bsums, boffs, binTotal, binStart, nb);
  scan_add_place<<<nb, 256, 0, stream>>>(rowstart, boffs, cursor, counts, binStart, blockBase, perm, N, E);
  scatter_kernel<<<(E + 255) / 256, 256, 0, stream>>>(src, dst, cursor, csr, E);

  // ---- weight transposes (into concatenated layouts) + x conversion ----
  {
    WPack wp;
    const float* ins[6] = {W1l, W1r, W2l, W2r, W3l, W3r};
    unsigned short* outs[6] = {Wc1, Wc1 + 256 * 128, Wc2, Wc2 + 256 * 256, Wc3, Wc3 + 64 * 256};
    int Ks[6] = {F0, F0, 256, 256, 256, 256};
    int Ns[6] = {256, 256, 256, 256, 64, 64};
    int acc0 = 0;
    for (int s = 0; s < 6; ++s) {
      wp.in[s] = ins[s]; wp.out[s] = outs[s]; wp.K[s] = Ks[s]; wp.Ncol[s] = Ns[s];
      wp.start[s] = acc0; acc0 += Ks[s] * Ns[s];
    }
    wp.start[6] = acc0;
    convert_all<<<(acc0 + 255) / 256, 256, 0, stream>>>(wp);
  }
  {
    int n4 = (N * F0) / 4;
    convert_x<<<(n4 + 255) / 256, 256, 0, stream>>>(x, xbf, n4);
  }

  int ne = (N + 3) / 4;

  // ---- conv1: K=128; single cat-GEMM (BN=256, 2 y-blocks) ----
  gemm_cat<256, 256><<<dim3(gx, 2), 512, 0, stream>>>(xbf, Wc1, bufA, bufB, N, F0);
  edge_agg4<false, true><<<ne, 256, 0, stream>>>(bufA, bufB, a1, b1, rowstart, csr, perm, bufH, N);

  // ---- conv2: K=256 ----
  gemm_cat<256, 256><<<dim3(gx, 2), 512, 0, stream>>>(bufH, Wc2, bufA, bufB, N, 256);
  edge_agg4<true, true><<<ne, 256, 0, stream>>>(bufA, bufB, a2, b2, rowstart, csr, perm, bufH, N);

  // ---- conv3: K=256, 64+64 cols (BN=128, 1 y-block) ----
  gemm_cat<128, 64><<<dim3(gx, 1), 512, 0, stream>>>(bufH, Wc3, bufA, bufB, N, 256);
  edge_agg1<true, false><<<ne, 256, 0, stream>>>(bufA, bufB, a3, b3, rowstart, csr, perm, bufH, N);

  // ---- fused mean pool + MLP head + softmax ----
  pool_mlp<<<G, 256, 0, stream>>>(bufH, batch, lw1, lb1, lw2, lb2, lw3, lb3,
                                  (float*)d_out, N);
}